// Round 9
// baseline (39329.327 us; speedup 1.0000x reference)
//
#include <hip/hip_runtime.h>
#include <cmath>

#define NWG 256
#define NT  512

typedef unsigned long long u64;
typedef unsigned short u16;
typedef unsigned int u32;

// ---------------- workspace layout (float offsets) ----------------
static constexpr size_t XT_   = 8192;                        // f32 [t][k][b]      2,097,152
static constexpr size_t XB_   = XT_   + 2097152;             // u16 [t][b][64k]
static constexpr size_t H1T_  = XB_   + 1048576;             // f32 [t][k][b]      16,777,216
static constexpr size_t ENCQ_ = H1T_  + 16777216;            // u16 [b][512k][512s]
static constexpr size_t HST_  = ENCQ_ + 8388608;             // f32 [d][buf][j][b]
static constexpr size_t HF_   = HST_  + 65536;               // f32 [512k][64b]
static constexpr size_t CF_   = HF_   + 32768;               // f32 [512k][64b]
static constexpr size_t HB_   = CF_   + 32768;               // u16 [2buf][64b][512k]
static constexpr size_t CTXB_ = HB_   + 32768;               // u16 [64b][1024]
static constexpr size_t SCP_  = CTXB_ + 32768;               // f32 [32cl][2b][2hc][8sl][512s]
static constexpr size_t PROJ_ = SCP_  + 524288;              // f32 [2buf][64b][8sl]
static constexpr size_t WDQ_  = PROJ_ + 1024;                // u64 [8sl][1600k][64p]

// ---------------- LDS layout (float offsets) ----------------
static constexpr int SLAB_F = 0;       // u32 [2b][64u][256c] swizzled  32768 fl
static constexpr int WSM_F  = 32768;   // f32 [2b][2hc][512s]           2048 fl
static constexpr int ACTS_F = 34816;   // u32 [1600]                    1600 fl
static constexpr int RED_F  = 36416;   // f32 [2048]
static constexpr int GTS_F  = 38464;   // f32 [512]
static constexpr int BI_F   = 38976;   // f32 [256]
static constexpr int HCL_F  = 39232;   // f32 h[2][64] c[2][64]
static constexpr int CXL_F  = 39488;   // f32 [2][2][64]
static constexpr int WPS_F  = 39744;   // f32 [64]
static constexpr int SMX_F  = 39808;   // f32 [64]
static constexpr int SMEM_F = 39872;   // 159,488 B
// encoder aliases (time-disjoint): WLe@0 (6144), REDe@6144 (4096), BIe@10240 (8)
static constexpr int WLE_F = 0, REDE_F = 6144, BIE_F = 10240;

__device__ __forceinline__ float sigm(float v) { return 1.f / (1.f + expf(-v)); }
__device__ __forceinline__ u16 f2bf(float f) {
  u32 u = __float_as_uint(f);
  u += 0x7fffu + ((u >> 16) & 1u);
  return (u16)(u >> 16);
}
__device__ __forceinline__ float bf2f(u16 h) { return __uint_as_float((u32)h << 16); }
__device__ __forceinline__ u64 pk4(const float* p) {
  return (u64)f2bf(p[0]) | ((u64)f2bf(p[1]) << 16) | ((u64)f2bf(p[2]) << 32) | ((u64)f2bf(p[3]) << 48);
}

__device__ __forceinline__ unsigned uld(unsigned* p) {
  return __hip_atomic_load(p, __ATOMIC_RELAXED, __HIP_MEMORY_SCOPE_AGENT);
}
__device__ __forceinline__ unsigned uadd(unsigned* p) {
  return __hip_atomic_fetch_add(p, 1u, __ATOMIC_RELAXED, __HIP_MEMORY_SCOPE_AGENT);
}
__device__ __forceinline__ float ald(const float* p) {
  return __hip_atomic_load(p, __ATOMIC_RELAXED, __HIP_MEMORY_SCOPE_AGENT);
}
__device__ __forceinline__ void ast(float* p, float v) {
  __hip_atomic_store(p, v, __ATOMIC_RELAXED, __HIP_MEMORY_SCOPE_AGENT);
}
__device__ __forceinline__ u64 a64ld(const u64* p) {
  return __hip_atomic_load(p, __ATOMIC_RELAXED, __HIP_MEMORY_SCOPE_AGENT);
}
__device__ __forceinline__ void a64st(u64* p, u64 v) {
  __hip_atomic_store(p, v, __ATOMIC_RELAXED, __HIP_MEMORY_SCOPE_AGENT);
}
__device__ __forceinline__ void acqf() { __builtin_amdgcn_fence(__ATOMIC_ACQUIRE, "agent"); }
__device__ __forceinline__ void relf() { __builtin_amdgcn_fence(__ATOMIC_RELEASE, "agent"); }

// full-grid barrier WITH fences (phase boundaries only)
__device__ __forceinline__ void fullbar(unsigned* bar, int wg) {
  __syncthreads();
  if (threadIdx.x == 0) {
    relf();
    unsigned g = uld(bar);
    if (((uadd(&bar[32 + (wg >> 3) * 32]) + 1) & 7) == 0)
      if (((uadd(&bar[1056 + (wg >> 6) * 32]) + 1) & 7) == 0)
        if (((uadd(&bar[1184]) + 1) & 3) == 0)
          uadd(bar);
    while (uld(bar) == g) __builtin_amdgcn_s_sleep(4);
    acqf();
  }
  __syncthreads();
}

// direction-local 128-WG relaxed barrier, fence-free
__device__ __forceinline__ void dbar(unsigned* base, int wgl) {
  __syncthreads();
  if (threadIdx.x == 0) {
    unsigned g = uld(base);
    if (((uadd(&base[32 + (wgl >> 3) * 32]) + 1) & 7) == 0)
      if (((uadd(&base[544]) + 1) & 15) == 0)
        uadd(base);
    while (uld(base) == g) __builtin_amdgcn_s_sleep(1);
  }
  __syncthreads();
}

// 8-WG relaxed minibar, fence-free
__device__ __forceinline__ void mbar8(unsigned* base) {
  __syncthreads();
  if (threadIdx.x == 0) {
    unsigned g = uld(base);
    if (((uadd(&base[32]) + 1) & 7) == 0) uadd(base);
    while (uld(base) == g) __builtin_amdgcn_s_sleep(1);
  }
  __syncthreads();
}

// encoder gate-GEMM K-segment, f32 cached activations
template<int N>
__device__ __forceinline__ void dot_seg(float (&acc)[4][2], const float* kb,
                                        const float* wl, int rq, int bq) {
#pragma unroll 16
  for (int i = 0; i < N; ++i) {
    float2 hv = *(const float2*)(kb + (size_t)i * 64 + 2 * bq);
    float4 wv = *(const float4*)(wl + i * 8 + rq * 4);
    acc[0][0] = fmaf(wv.x, hv.x, acc[0][0]); acc[0][1] = fmaf(wv.x, hv.y, acc[0][1]);
    acc[1][0] = fmaf(wv.y, hv.x, acc[1][0]); acc[1][1] = fmaf(wv.y, hv.y, acc[1][1]);
    acc[2][0] = fmaf(wv.z, hv.x, acc[2][0]); acc[2][1] = fmaf(wv.z, hv.y, acc[2][1]);
    acc[3][0] = fmaf(wv.w, hv.x, acc[3][0]); acc[3][1] = fmaf(wv.w, hv.y, acc[3][1]);
  }
}

// h-state via relaxed b64 agent-atomic loads
template<int N>
__device__ __forceinline__ void dot_at2(float (&acc)[4][2], const float* kb,
                                        const float* wl, int rq, int bq) {
#pragma unroll 16
  for (int i = 0; i < N; ++i) {
    u64 v = a64ld((const u64*)(kb + (size_t)i * 64 + 2 * bq));
    float h0 = __uint_as_float((u32)v);
    float h1 = __uint_as_float((u32)(v >> 32));
    float4 wv = *(const float4*)(wl + i * 8 + rq * 4);
    acc[0][0] = fmaf(wv.x, h0, acc[0][0]); acc[0][1] = fmaf(wv.x, h1, acc[0][1]);
    acc[1][0] = fmaf(wv.y, h0, acc[1][0]); acc[1][1] = fmaf(wv.y, h1, acc[1][1]);
    acc[2][0] = fmaf(wv.z, h0, acc[2][0]); acc[2][1] = fmaf(wv.z, h1, acc[2][1]);
    acc[3][0] = fmaf(wv.w, h0, acc[3][0]); acc[3][1] = fmaf(wv.w, h1, acc[3][1]);
  }
}

__device__ void fill_wl(float* WLs, float* BIs,
                        const float* Wih, const float* Whh,
                        const float* bih, const float* bhh,
                        int KI, int KH, int gstride, int u0, int K) {
  for (int idx = threadIdx.x; idx < K * 8; idx += NT) {
    int k = idx >> 3, slot = idx & 7;
    int row = (slot >> 1) * gstride + u0 + (slot & 1);
    WLs[k * 8 + slot] = (k < KI) ? Wih[(size_t)row * KI + k]
                                 : Whh[(size_t)row * KH + (k - KI)];
  }
  if (threadIdx.x < 8) {
    int row = ((int)threadIdx.x >> 1) * gstride + u0 + ((int)threadIdx.x & 1);
    BIs[threadIdx.x] = bih[row] + bhh[row];
  }
  __syncthreads();
}

extern "C" __global__ void __launch_bounds__(NT, 1)
seq2seq_ker(const float* __restrict__ x,
            const float* __restrict__ Wih0, const float* __restrict__ Whh0,
            const float* __restrict__ bih0, const float* __restrict__ bhh0,
            const float* __restrict__ Wih1, const float* __restrict__ Whh1,
            const float* __restrict__ bih1, const float* __restrict__ bhh1,
            const float* __restrict__ Wihd, const float* __restrict__ Whhd,
            const float* __restrict__ bihd, const float* __restrict__ bhhd,
            const float* __restrict__ Wp,   const float* __restrict__ bp,
            float* out, float* ws) {
  extern __shared__ float smem[];
  unsigned* bar = (unsigned*)ws;
  const int tid = threadIdx.x;
  const int wg  = blockIdx.x;
  const int gtid = wg * NT + tid;
  const int lane = tid & 63, q = tid >> 6;
  const int rq = lane & 1, bq = lane >> 1;

  // ---------- prologue ----------
  for (size_t i = gtid; i < (size_t)512 * 64 * 64; i += (size_t)NWG * NT) {
    int k = (int)(i & 63), tt2 = (int)((i >> 6) & 511), bb = (int)(i >> 15);
    float v = x[i];
    ws[XT_ + (size_t)tt2 * 4096 + k * 64 + bb] = v;
    ((u16*)(ws + XB_))[((size_t)tt2 * 64 + bb) * 64 + k] = f2bf(v);
  }
  // decoder weights: [sl][1600 k][64 p] u64, p packs 4 local rows
  for (size_t idx = gtid; idx < (size_t)8 * 1600 * 64; idx += (size_t)NWG * NT) {
    int p = (int)(idx & 63);
    int k = (int)((idx >> 6) % 1600);
    int sl = (int)((idx >> 6) / 1600);
    u64 v = 0;
#pragma unroll
    for (int j = 0; j < 4; ++j) {
      int r = 4 * p + j;
      int row = (r >> 6) * 512 + sl * 64 + (r & 63);
      float wv = (k < 1088) ? Wihd[(size_t)row * 1088 + k]
                            : Whhd[(size_t)row * 512 + (k - 1088)];
      v |= (u64)f2bf(wv) << (16 * j);
    }
    ((u64*)(ws + WDQ_))[idx] = v;
  }
  if (gtid < 65536) ast(ws + HST_ + gtid, 0.f);

  // ---------- encoder ----------
  const int d  = wg >> 7;
  const int u0 = (wg & 127) * 2;
  const int wgl = wg & 127;
  unsigned* dirbar = bar + 2048 + d * 1024;
  float* WLe = smem + WLE_F;
  float* REDe = smem + REDE_F;
  float* BIe = smem + BIE_F;

  float cReg = 0.f, hReg = 0.f;

  for (int layer = 0; layer < 2; ++layer) {
    if (layer == 0)
      fill_wl(WLe, BIe, Wih0 + (size_t)d * 1024 * 64,  Whh0 + (size_t)d * 1024 * 256,
              bih0 + d * 1024, bhh0 + d * 1024, 64, 256, 256, u0, 320);
    else
      fill_wl(WLe, BIe, Wih1 + (size_t)d * 1024 * 512, Whh1 + (size_t)d * 1024 * 256,
              bih1 + d * 1024, bhh1 + d * 1024, 512, 256, 256, u0, 768);
    fullbar(bar, wg);

    for (int t = 0; t < 512; ++t) {
      const int cur = t & 1, nxt = cur ^ 1;
      const int tt = d ? (511 - t) : t;
      float acc[4][2] = {{0.f,0.f},{0.f,0.f},{0.f,0.f},{0.f,0.f}};
      const float* hbase = ws + HST_ + ((size_t)(d * 2 + cur) * 256) * 64;
      if (layer == 0) {
        const float* xb = ws + XT_ + (size_t)tt * 4096;
        switch (q) {
          case 0: dot_seg<40>(acc, xb, WLe, rq, bq); break;
          case 1: dot_seg<24>(acc, xb + 40*64, WLe + 40*8, rq, bq);
                  dot_at2<16>(acc, hbase, WLe + 64*8, rq, bq); break;
          case 2: dot_at2<40>(acc, hbase + 16*64,  WLe + 80*8,  rq, bq); break;
          case 3: dot_at2<40>(acc, hbase + 56*64,  WLe + 120*8, rq, bq); break;
          case 4: dot_at2<40>(acc, hbase + 96*64,  WLe + 160*8, rq, bq); break;
          case 5: dot_at2<40>(acc, hbase + 136*64, WLe + 200*8, rq, bq); break;
          case 6: dot_at2<40>(acc, hbase + 176*64, WLe + 240*8, rq, bq); break;
          default:dot_at2<40>(acc, hbase + 216*64, WLe + 280*8, rq, bq); break;
        }
      } else {
        const float* ib = ws + H1T_ + (size_t)tt * 512 * 64;
        switch (q) {
          case 0: dot_seg<96>(acc, ib,          WLe,         rq, bq); break;
          case 1: dot_seg<96>(acc, ib + 96*64,  WLe + 96*8,  rq, bq); break;
          case 2: dot_seg<96>(acc, ib + 192*64, WLe + 192*8, rq, bq); break;
          case 3: dot_seg<96>(acc, ib + 288*64, WLe + 288*8, rq, bq); break;
          case 4: dot_seg<96>(acc, ib + 384*64, WLe + 384*8, rq, bq); break;
          case 5: dot_seg<32>(acc, ib + 480*64, WLe + 480*8, rq, bq);
                  dot_at2<64>(acc, hbase, WLe + 512*8, rq, bq); break;
          case 6: dot_at2<96>(acc, hbase + 64*64,  WLe + 576*8, rq, bq); break;
          default:dot_at2<96>(acc, hbase + 160*64, WLe + 672*8, rq, bq); break;
        }
      }
#pragma unroll
      for (int r = 0; r < 4; ++r)
        *(float2*)&REDe[((q * 8 + rq * 4 + r) * 64) + 2 * bq] = make_float2(acc[r][0], acc[r][1]);
      __syncthreads();
      if (tid < 128) {
        int b = tid & 63, u = tid >> 6;
        float g4[4];
#pragma unroll
        for (int g = 0; g < 4; ++g) {
          int slot = g * 2 + u;
          float s = BIe[slot];
#pragma unroll
          for (int qq = 0; qq < 8; ++qq) s += REDe[(qq * 8 + slot) * 64 + b];
          g4[g] = s;
        }
        float iv = sigm(g4[0]), fv = sigm(g4[1]), gv = tanhf(g4[2]), ov = sigm(g4[3]);
        int j = u0 + u, kk = d * 256 + j;
        float c1 = fv * cReg + iv * gv;
        cReg = c1;
        float h1 = ov * tanhf(c1);
        hReg = h1;
        ast(ws + HST_ + ((size_t)(d * 2 + nxt) * 256 + j) * 64 + b, h1);
        if (layer == 0) ws[H1T_ + ((size_t)tt * 512 + kk) * 64 + b] = h1;
        else            ((u16*)(ws + ENCQ_))[((size_t)b * 512 + kk) * 512 + tt] = f2bf(h1);
      }
      dbar(dirbar, wgl);
    }
    if (layer == 0) {
      if (tid < 128) {
        int b = tid & 63, u = tid >> 6;
        ast(ws + HST_ + ((size_t)(d * 2 + 0) * 256 + u0 + u) * 64 + b, 0.f);
        ast(ws + HST_ + ((size_t)(d * 2 + 1) * 256 + u0 + u) * 64 + b, 0.f);
        cReg = 0.f;
      }
    }
  }

  if (tid < 128) {
    int b = tid & 63, u = tid >> 6;
    int kd = d * 256 + u0 + u;
    ast(ws + HF_ + (size_t)kd * 64 + b, hReg);
    ast(ws + CF_ + (size_t)kd * 64 + b, cReg);
  }
  fullbar(bar, wg);   // ENCQ/H1T/XB/WDQ + HF/CF visible

  // ---------- decoder: 32 clusters x 8 WGs, 2 batches each ----------
  const int cl = wg >> 3, sl = wg & 7;   // sl == wg%8 == XCD -> weight slice L2-resident
  const int b0 = 2 * cl;
  unsigned* mb = bar + 4096 + cl * 64;

  u32* slab = (u32*)smem;
  float* wsmf = smem + WSM_F;            // f32 [2b][2hc][512s]
  u32* act32 = (u32*)(smem + ACTS_F);
  float* red = smem + RED_F;
  float* gts = smem + GTS_F;
  float* bi  = smem + BI_F;
  float* hcl = smem + HCL_F;   // h[2][64] then c[2][64]
  float* cxl = smem + CXL_F;
  float* wps = smem + WPS_F;
  float* smx = smem + SMX_F;

  // slab load (swizzled), bias, Wp slice, h0/c0
  for (int bb = 0; bb < 2; ++bb) {
    const u32* src = (const u32*)((const u16*)(ws + ENCQ_)) + ((size_t)(b0 + bb) * 512 + sl * 64) * 256;
    for (int i = tid; i < 16384; i += NT) {
      int u = i >> 8, c = i & 255;
      slab[(bb * 64 + u) * 256 + (c ^ (u & 31))] = src[i];
    }
  }
  if (tid < 256) {
    int row = (tid >> 6) * 512 + sl * 64 + (tid & 63);
    bi[tid] = bihd[row] + bhhd[row];
  }
  if (tid < 64) wps[tid] = Wp[sl * 64 + tid];
  if (tid < 128) {
    int bb = tid >> 6, u = tid & 63;
    hcl[bb * 64 + u]       = ald(ws + HF_ + (size_t)(sl * 64 + u) * 64 + (b0 + bb));
    hcl[128 + bb * 64 + u] = ald(ws + CF_ + (size_t)(sl * 64 + u) * 64 + (b0 + bb));
  }
  __syncthreads();
  if (tid < 32) {
    int bb = tid >> 4, q4 = tid & 15;
    a64st((u64*)((u16*)(ws + HB_)) + ((size_t)0 * 64 + b0 + bb) * 128 + sl * 16 + q4,
          pk4(&hcl[bb * 64 + 4 * q4]));
  }
  const float bp0 = bp[0];

  for (int t = 0; t < 512; ++t) {
    // ===== scores for my 64-unit slice, both batches (all local) =====
    {
      int c = tid >> 1, sh = (tid & 1) * 16;
      float a00 = 0.f, a01 = 0.f, a10 = 0.f, a11 = 0.f;
#pragma unroll 8
      for (int u = 0; u < 64; ++u) {
        int sw = c ^ (u & 31);
        u32 e0 = slab[u * 256 + sw];
        u32 e1 = slab[(64 + u) * 256 + sw];
        float f0 = bf2f((u16)(e0 >> sh));
        float f1 = bf2f((u16)(e1 >> sh));
        a00 = fmaf(f0, hcl[u], a00);        a01 = fmaf(f0, hcl[128 + u], a01);
        a10 = fmaf(f1, hcl[64 + u], a10);   a11 = fmaf(f1, hcl[192 + u], a11);
      }
      size_t base = SCP_ + (((size_t)cl * 2) * 2 * 8 + sl) * 512 + tid;
      ast(ws + base,            a00);   // b=0 hc=0
      ast(ws + base + 8 * 512,  a01);   // b=0 hc=1
      ast(ws + base + 16 * 512, a10);   // b=1 hc=0
      ast(ws + base + 24 * 512, a11);   // b=1 hc=1
    }
    mbar8(mb);

    // out[b][t-1] writer (PROJ published end of step t-1)
    if (sl == 0 && tid >= 510 && t > 0) {
      int bb = tid - 510;
      float v = bp0;
#pragma unroll
      for (int s8 = 0; s8 < 8; ++s8)
        v += ald(ws + PROJ_ + ((size_t)(t & 1) * 64 + b0 + bb) * 8 + s8);
      out[(size_t)(b0 + bb) * 512 + (t - 1)] = v;
    }

    // ===== reduce slices + softmax (replicated), f32 weights in LDS =====
    {
      int bb = tid >> 8, i2 = tid & 255;
      float v00 = 0.f, v01 = 0.f, v10 = 0.f, v11 = 0.f;   // [hc][s-pair]
      const float* base = ws + SCP_ + (((size_t)cl * 2 + bb) * 2) * 8 * 512;
#pragma unroll
      for (int s8 = 0; s8 < 8; ++s8) {
        v00 += ald(base + (size_t)s8 * 512 + 2 * i2);
        v01 += ald(base + (size_t)s8 * 512 + 2 * i2 + 1);
        v10 += ald(base + (size_t)(8 + s8) * 512 + 2 * i2);
        v11 += ald(base + (size_t)(8 + s8) * 512 + 2 * i2 + 1);
      }
      float m0 = fmaxf(v00, v01), m1 = fmaxf(v10, v11);
#pragma unroll
      for (int o = 1; o <= 32; o <<= 1) { m0 = fmaxf(m0, __shfl_xor(m0, o)); m1 = fmaxf(m1, __shfl_xor(m1, o)); }
      if (lane == 0) { smx[q] = m0; smx[8 + q] = m1; }
      __syncthreads();
      m0 = smx[bb * 4]; m1 = smx[8 + bb * 4];
#pragma unroll
      for (int wv = 1; wv < 4; ++wv) { m0 = fmaxf(m0, smx[bb * 4 + wv]); m1 = fmaxf(m1, smx[8 + bb * 4 + wv]); }
      float e00 = expf(v00 - m0), e01 = expf(v01 - m0);
      float e10 = expf(v10 - m1), e11 = expf(v11 - m1);
      float z0 = e00 + e01, z1 = e10 + e11;
#pragma unroll
      for (int o = 1; o <= 32; o <<= 1) { z0 += __shfl_xor(z0, o); z1 += __shfl_xor(z1, o); }
      if (lane == 0) { smx[16 + q] = z0; smx[24 + q] = z1; }
      __syncthreads();
      z0 = 0.f; z1 = 0.f;
#pragma unroll
      for (int wv = 0; wv < 4; ++wv) { z0 += smx[16 + bb * 4 + wv]; z1 += smx[24 + bb * 4 + wv]; }
      wsmf[(bb * 2 + 0) * 512 + 2 * i2]     = e00 / z0;
      wsmf[(bb * 2 + 0) * 512 + 2 * i2 + 1] = e01 / z0;
      wsmf[(bb * 2 + 1) * 512 + 2 * i2]     = e10 / z1;
      wsmf[(bb * 2 + 1) * 512 + 2 * i2 + 1] = e11 / z1;
    }
    __syncthreads();

    // ===== ctx for my slice over all s (local) =====
    {
      int bb = q >> 2, oct = q & 3, u = lane;
      float ch = 0.f, cc = 0.f;
#pragma unroll 8
      for (int i = 0; i < 64; ++i) {
        int c = oct * 64 + i;
        u32 e = slab[(bb * 64 + u) * 256 + (c ^ (u & 31))];
        float e0 = bf2f((u16)e), e1 = bf2f((u16)(e >> 16));
        int s = 2 * c;
        ch += e0 * wsmf[(bb * 2 + 0) * 512 + s] + e1 * wsmf[(bb * 2 + 0) * 512 + s + 1];
        cc += e0 * wsmf[(bb * 2 + 1) * 512 + s] + e1 * wsmf[(bb * 2 + 1) * 512 + s + 1];
      }
      red[((bb * 64 + u) * 2 + 0) * 4 + oct] = ch;
      red[((bb * 64 + u) * 2 + 1) * 4 + oct] = cc;
    }
    __syncthreads();
    if (tid < 256) {
      int bb = tid >> 7, u = (tid >> 1) & 63, hc = tid & 1;
      float v = red[((bb * 64 + u) * 2 + hc) * 4 + 0] + red[((bb * 64 + u) * 2 + hc) * 4 + 1]
              + red[((bb * 64 + u) * 2 + hc) * 4 + 2] + red[((bb * 64 + u) * 2 + hc) * 4 + 3];
      cxl[(bb * 2 + hc) * 64 + u] = v;
    }
    __syncthreads();
    // FIX (r8 bug): each (bb,hc) slice is 16 u64s -> needs 64 threads, q4 in 0..15
    if (tid < 64) {
      int bb = tid >> 5, hc = (tid >> 4) & 1, q4 = tid & 15;
      a64st((u64*)((u16*)(ws + CTXB_)) + (size_t)(b0 + bb) * 256 + hc * 128 + sl * 16 + q4,
            pk4(&cxl[(bb * 2 + hc) * 64 + 4 * q4]));
    }
    mbar8(mb);

    // ===== stage act (bf16, both batches packed per u32) =====
    if (tid < 400) {
      u64 vb[2];
#pragma unroll
      for (int bb = 0; bb < 2; ++bb) {
        int b = b0 + bb;
        if (tid < 16)
          vb[bb] = a64ld((const u64*)((const u16*)(ws + XB_)) + ((size_t)t * 64 + b) * 16 + tid);
        else if (tid < 272)
          vb[bb] = a64ld((const u64*)((const u16*)(ws + CTXB_)) + (size_t)b * 256 + (tid - 16));
        else
          vb[bb] = a64ld((const u64*)((const u16*)(ws + HB_)) + ((size_t)(t & 1) * 64 + b) * 128 + (tid - 272));
      }
#pragma unroll
      for (int j = 0; j < 4; ++j)
        act32[4 * tid + j] = (u32)(u16)(vb[0] >> (16 * j)) | ((u32)(u16)(vb[1] >> (16 * j)) << 16);
    }
    __syncthreads();

    // ===== gate GEMM: 256 rows x K=1600 x 2 batches, weights streamed once =====
    {
      int kq = tid >> 7, bb = (tid >> 6) & 1, p = tid & 63;
      const u64* wq = (const u64*)(ws + WDQ_) + (size_t)sl * 1600 * 64;
      float a0 = 0.f, a1 = 0.f, a2 = 0.f, a3 = 0.f;
      int k0 = kq * 400, shb = bb * 16;
#pragma unroll 16
      for (int i = 0; i < 400; ++i) {
        int k = k0 + i;
        u64 wv = wq[(size_t)k * 64 + p];
        float a = bf2f((u16)(act32[k] >> shb));
        a0 = fmaf(bf2f((u16)wv), a, a0);
        a1 = fmaf(bf2f((u16)(wv >> 16)), a, a1);
        a2 = fmaf(bf2f((u16)(wv >> 32)), a, a2);
        a3 = fmaf(bf2f((u16)(wv >> 48)), a, a3);
      }
      *(float4*)&red[tid * 4] = make_float4(a0, a1, a2, a3);
    }
    __syncthreads();
    {
      int bb = tid >> 8, r = tid & 255, p = r >> 2, v = r & 3;
      float g = bi[r];
#pragma unroll
      for (int kq = 0; kq < 4; ++kq) g += red[(kq * 128 + bb * 64 + p) * 4 + v];
      gts[tid] = g;
    }
    __syncthreads();
    if (tid < 128) {
      int bb = tid >> 6, u = tid & 63;
      float iv = sigm(gts[bb * 256 + u]);
      float fv = sigm(gts[bb * 256 + 64 + u]);
      float gv = tanhf(gts[bb * 256 + 128 + u]);
      float ov = sigm(gts[bb * 256 + 192 + u]);
      float c1 = fv * hcl[128 + bb * 64 + u] + iv * gv;
      hcl[128 + bb * 64 + u] = c1;
      float h1 = ov * tanhf(c1);
      hcl[bb * 64 + u] = h1;
      float pv = h1 * wps[u];
#pragma unroll
      for (int o = 1; o <= 32; o <<= 1) pv += __shfl_xor(pv, o);
      if (u == 0)
        ast(ws + PROJ_ + ((size_t)((t + 1) & 1) * 64 + b0 + bb) * 8 + sl, pv);
    }
    __syncthreads();
    if (tid < 32) {
      int bb = tid >> 4, q4 = tid & 15;
      a64st((u64*)((u16*)(ws + HB_)) + ((size_t)((t + 1) & 1) * 64 + b0 + bb) * 128 + sl * 16 + q4,
            pk4(&hcl[bb * 64 + 4 * q4]));
    }
  }

  // ---------- epilogue ----------
  mbar8(mb);
  if (sl == 0 && tid < 2) {
    int bb = tid;
    float v = bp0;
#pragma unroll
    for (int s8 = 0; s8 < 8; ++s8)
      v += ald(ws + PROJ_ + ((size_t)0 * 64 + b0 + bb) * 8 + s8);
    out[(size_t)(b0 + bb) * 512 + 511] = v;
  }
}

extern "C" void kernel_launch(void* const* d_in, const int* in_sizes, int n_in,
                              void* d_out, int out_size, void* d_ws, size_t ws_size,
                              hipStream_t stream) {
  const float* x    = (const float*)d_in[0];
  const float* Wih0 = (const float*)d_in[1];
  const float* Whh0 = (const float*)d_in[2];
  const float* bih0 = (const float*)d_in[3];
  const float* bhh0 = (const float*)d_in[4];
  const float* Wih1 = (const float*)d_in[5];
  const float* Whh1 = (const float*)d_in[6];
  const float* bih1 = (const float*)d_in[7];
  const float* bhh1 = (const float*)d_in[8];
  const float* Wihd = (const float*)d_in[9];
  const float* Whhd = (const float*)d_in[10];
  const float* bihd = (const float*)d_in[11];
  const float* bhhd = (const float*)d_in[12];
  const float* Wp   = (const float*)d_in[13];
  const float* bp   = (const float*)d_in[14];
  float* out = (float*)d_out;
  float* ws  = (float*)d_ws;
  (void)ws_size; (void)n_in; (void)in_sizes; (void)out_size;

  hipMemsetAsync(d_ws, 0, 32768, stream);

  hipFuncSetAttribute((const void*)seq2seq_ker,
                      hipFuncAttributeMaxDynamicSharedMemorySize, SMEM_F * 4);

  hipLaunchKernelGGL(seq2seq_ker, dim3(NWG), dim3(NT), SMEM_F * 4, stream,
                     x, Wih0, Whh0, bih0, bhh0, Wih1, Whh1, bih1, bhh1,
                     Wihd, Whhd, bihd, bhhd, Wp, bp, out, ws);
}